// Round 1
// baseline (200.254 us; speedup 1.0000x reference)
//
#include <hip/hip_runtime.h>
#include <math.h>

typedef __bf16 bf16;
typedef __attribute__((ext_vector_type(8))) __bf16 bf16x8;
typedef __attribute__((ext_vector_type(4))) __bf16 bf16x4;
typedef __attribute__((ext_vector_type(4))) float f32x4;

// ---------------- column batchnorm stats (deterministic, two-pass) ----------
__global__ void colstats_partial(const float* __restrict__ X, int C_, int rows_per_chunk,
                                 float* __restrict__ psum, float* __restrict__ psq)
{
    int col = blockIdx.x * blockDim.x + threadIdx.x;
    int r0  = blockIdx.y * rows_per_chunk;
    float s = 0.f, q = 0.f;
    for (int r = 0; r < rows_per_chunk; ++r) {
        float x = X[(long)(r0 + r) * C_ + col];
        s += x; q += x * x;
    }
    psum[blockIdx.y * C_ + col] = s;
    psq [blockIdx.y * C_ + col] = q;
}

__global__ void colstats_final(const float* __restrict__ psum, const float* __restrict__ psq,
                               int C_, int nch, const float* __restrict__ g, const float* __restrict__ b,
                               float* __restrict__ scale, float* __restrict__ shift, float n)
{
    int col = blockIdx.x * blockDim.x + threadIdx.x;
    float s = 0.f, q = 0.f;
    for (int ch = 0; ch < nch; ++ch) { s += psum[ch * C_ + col]; q += psq[ch * C_ + col]; }
    float m   = s / n;
    float v   = q / n - m * m;
    float inv = 1.0f / sqrtf(v + 1e-5f);
    float sc  = g[col] * inv;
    scale[col] = sc;
    shift[col] = b[col] - m * sc;
}

// y = bf16(x*scale[col] + shift[col]) , vectorized x4
__global__ void bn_apply_bf16(const float* __restrict__ X, const float* __restrict__ scale,
                              const float* __restrict__ shift, bf16* __restrict__ Y, int Cmask)
{
    long i = (long)blockIdx.x * blockDim.x + threadIdx.x;
    float4 x = ((const float4*)X)[i];
    int col = (int)((i * 4) & Cmask);
    float4 sc = *(const float4*)(scale + col);
    float4 sh = *(const float4*)(shift + col);
    bf16x4 y;
    y[0] = (bf16)(x.x * sc.x + sh.x);
    y[1] = (bf16)(x.y * sc.y + sh.y);
    y[2] = (bf16)(x.z * sc.z + sh.z);
    y[3] = (bf16)(x.w * sc.w + sh.w);
    ((bf16x4*)Y)[i] = y;
}

// in-place f32 x = x*scale[col]+shift[col]
__global__ void bn_apply_f32(float* __restrict__ X, const float* __restrict__ scale,
                             const float* __restrict__ shift, int Cmask)
{
    long i = (long)blockIdx.x * blockDim.x + threadIdx.x;
    float4 x = ((const float4*)X)[i];
    int col = (int)((i * 4) & Cmask);
    float4 sc = *(const float4*)(scale + col);
    float4 sh = *(const float4*)(shift + col);
    float4 r;
    r.x = x.x * sc.x + sh.x;
    r.y = x.y * sc.y + sh.y;
    r.z = x.z * sc.z + sh.z;
    r.w = x.w * sc.w + sh.w;
    ((float4*)X)[i] = r;
}

__global__ void pack2(const float* __restrict__ a, const float* __restrict__ b,
                      float* __restrict__ o, int n)
{
    int i = blockIdx.x * blockDim.x + threadIdx.x;
    o[i] = (i < n) ? a[i] : b[i - n];
}

// 64x64 LDS-tiled transpose + f32->bf16 of the three weight matrices (1024x1024)
__global__ void transpose_cvt(const float* __restrict__ W0, const float* __restrict__ W1,
                              const float* __restrict__ W2,
                              bf16* __restrict__ T0, bf16* __restrict__ T1, bf16* __restrict__ T2)
{
    const float* W; bf16* T;
    if (blockIdx.z == 0)      { W = W0; T = T0; }
    else if (blockIdx.z == 1) { W = W1; T = T1; }
    else                      { W = W2; T = T2; }
    __shared__ float tile[64][65];
    const int bx = blockIdx.x * 64, by = blockIdx.y * 64;
    const int tx = threadIdx.x, ty = threadIdx.y;
#pragma unroll
    for (int i = 0; i < 16; ++i)
        tile[ty + i * 4][tx] = W[(long)(by + ty + i * 4) * 1024 + bx + tx];
    __syncthreads();
#pragma unroll
    for (int i = 0; i < 16; ++i)
        T[(long)(bx + ty + i * 4) * 1024 + by + tx] = (bf16)tile[tx][ty + i * 4];
}

// ------------- relative positional encoding bias rel[img][i][j] -------------
// Replicates the reference's concat+reshape quirk: for output col j, block
// b=j>>7 selects {dx,dy,dw,dh}, and the 4 components are source cols 4j-b*512..+3.
__global__ __launch_bounds__(256)
void rel_pe_kernel(const float* __restrict__ boxes, const float* __restrict__ Wr,
                   const float* __restrict__ brp, float* __restrict__ rel)
{
    const int img = blockIdx.y;
    const int i   = blockIdx.x;
    __shared__ float cx[512], cy[512], wv[512], hv[512];
    __shared__ float wsn[64], wcs[64], tks[16];
    const float* bx = boxes + (long)img * 2048;
    for (int t = threadIdx.x; t < 512; t += 256) {
        float x = bx[t * 4 + 0], y = bx[t * 4 + 1], ww = bx[t * 4 + 2], hh = bx[t * 4 + 3];
        cx[t] = x + 0.5f * ww; cy[t] = y + 0.5f * hh; wv[t] = ww; hv[t] = hh;
    }
    if (threadIdx.x < 64) {
        int c = threadIdx.x >> 4, k = threadIdx.x & 15;
        wsn[threadIdx.x] = Wr[c * 32 + k];        // sin weights
        wcs[threadIdx.x] = Wr[c * 32 + 16 + k];   // cos weights
    }
    if (threadIdx.x < 16)
        tks[threadIdx.x] = exp2f(-1.24572303558f * (float)threadIdx.x); // 1000^(-k/8)
    __syncthreads();
    const float br  = brp[0];
    const float cxi = cx[i], cyi = cy[i], wi = wv[i], hi = hv[i];
    for (int j = threadIdx.x; j < 512; j += 256) {
        const int b  = j >> 7;
        const int jj = 4 * j - b * 512;
        float d[4];
#pragma unroll
        for (int c = 0; c < 4; ++c) {
            const int s = jj + c;
            float dv;
            if (b == 0)      dv = fmaxf(fabsf(cxi - cx[s]) / wv[s], 1e-3f);
            else if (b == 1) dv = fmaxf(fabsf(cyi - cy[s]) / hv[s], 1e-3f);
            else if (b == 2) dv = wi / wv[s];
            else             dv = hi / hv[s];
            d[c] = logf(dv);
        }
        float acc = br;
#pragma unroll
        for (int c = 0; c < 4; ++c)
#pragma unroll
            for (int k = 0; k < 16; ++k) {
                float s_, c_;
                __sincosf(d[c] * tks[k], &s_, &c_);
                acc += s_ * wsn[c * 16 + k] + c_ * wcs[c * 16 + k];
            }
        rel[((long)img * 512 + i) * 512 + j] = acc;
    }
}

// ---------------- row softmax (512 wide) f32 -> bf16 ------------------------
__global__ __launch_bounds__(256)
void softmax_rows(const float* __restrict__ S, bf16* __restrict__ P)
{
    const long row = blockIdx.x;
    const float* s = S + row * 512;
    const int t = threadIdx.x;
    float x0 = s[t], x1 = s[t + 256];
    float mx = fmaxf(x0, x1);
#pragma unroll
    for (int off = 32; off; off >>= 1) mx = fmaxf(mx, __shfl_xor(mx, off));
    __shared__ float redm[4], reds[4];
    if ((t & 63) == 0) redm[t >> 6] = mx;
    __syncthreads();
    mx = fmaxf(fmaxf(redm[0], redm[1]), fmaxf(redm[2], redm[3]));
    float e0 = __expf(x0 - mx), e1 = __expf(x1 - mx);
    float sm = e0 + e1;
#pragma unroll
    for (int off = 32; off; off >>= 1) sm += __shfl_xor(sm, off);
    if ((t & 63) == 0) reds[t >> 6] = sm;
    __syncthreads();
    sm = (reds[0] + reds[1]) + (reds[2] + reds[3]);
    float inv = 1.0f / sm;
    P[row * 512 + t]       = (bf16)(e0 * inv);
    P[row * 512 + t + 256] = (bf16)(e1 * inv);
}

// ---------------- MFMA GEMM: C = A(M,K) @ BT(N,K)^T -------------------------
// 128x128 tile, BK=32, 4 waves (2x2), 16x16x32 bf16 MFMA, global_load_lds staging.
__device__ __forceinline__ void stage_tile_128x32(const bf16* __restrict__ src_base, int ld,
                                                  int row0, int k0, bf16* lds_base, int w, int l)
{
#pragma unroll
    for (int t = 0; t < 2; ++t) {
        int rchunk = w * 32 + t * 16;   // 16 rows per instruction per wave
        const bf16* src = src_base + (long)(row0 + rchunk + (l >> 2)) * ld + k0 + (l & 3) * 8;
        __builtin_amdgcn_global_load_lds((__attribute__((address_space(1))) void*)src,
                                         (__attribute__((address_space(3))) void*)(lds_base + rchunk * 32),
                                         16, 0, 0);
    }
}

// MODE 0: bf16 out, +bias[col]   1: bf16 out, +bias[row]
// MODE 2: f32 out = acc*scale + rel[row,col]   3: f32 out
template <int MODE>
__global__ __launch_bounds__(256, 2)
void gemm_bt(const bf16* __restrict__ A, long sA, int lda,
             const bf16* __restrict__ B, long sB, int ldb,
             void* __restrict__ Cp, long sC, int ldc,
             int K,
             const float* __restrict__ bias,
             const float* __restrict__ rel, long sRel, float scale)
{
    __shared__ bf16 As[2][128 * 32];
    __shared__ bf16 Bs[2][128 * 32];
    const int img = blockIdx.z;
    const bf16* Ab = A + (long)img * sA;
    const bf16* Bb = B + (long)img * sB;
    const int bm = blockIdx.x * 128;
    const int bn = blockIdx.y * 128;
    const int tid = threadIdx.x;
    const int w = tid >> 6, l = tid & 63;
    const int wr = w >> 1, wc = w & 1;

    f32x4 acc[4][4];
#pragma unroll
    for (int i = 0; i < 4; ++i)
#pragma unroll
        for (int j = 0; j < 4; ++j) acc[i][j] = (f32x4){0.f, 0.f, 0.f, 0.f};

    const int nkt = K >> 5;
    stage_tile_128x32(Ab, lda, bm, 0, &As[0][0], w, l);
    stage_tile_128x32(Bb, ldb, bn, 0, &Bs[0][0], w, l);
    __syncthreads();

    const int fr = l & 15;
    const int ko = (l >> 4) * 8;

    for (int kt = 0; kt < nkt; ++kt) {
        const int cur = kt & 1;
        if (kt + 1 < nkt) {
            stage_tile_128x32(Ab, lda, bm, (kt + 1) << 5, &As[cur ^ 1][0], w, l);
            stage_tile_128x32(Bb, ldb, bn, (kt + 1) << 5, &Bs[cur ^ 1][0], w, l);
        }
        bf16x8 af[4], bfv[4];
#pragma unroll
        for (int mi = 0; mi < 4; ++mi)
            af[mi] = *(const bf16x8*)(&As[cur][(wr * 64 + mi * 16 + fr) * 32 + ko]);
#pragma unroll
        for (int ni = 0; ni < 4; ++ni)
            bfv[ni] = *(const bf16x8*)(&Bs[cur][(wc * 64 + ni * 16 + fr) * 32 + ko]);
#pragma unroll
        for (int mi = 0; mi < 4; ++mi)
#pragma unroll
            for (int ni = 0; ni < 4; ++ni)
                acc[mi][ni] = __builtin_amdgcn_mfma_f32_16x16x32_bf16(af[mi], bfv[ni], acc[mi][ni], 0, 0, 0);
        __syncthreads();
    }

    // C/D layout: col = lane&15, row = (lane>>4)*4 + reg   [HW-verified, guide §3]
    const int crow0 = bm + wr * 64 + (l >> 4) * 4;
    const int ccol0 = bn + wc * 64 + fr;
#pragma unroll
    for (int mi = 0; mi < 4; ++mi)
#pragma unroll
        for (int ni = 0; ni < 4; ++ni)
#pragma unroll
            for (int r = 0; r < 4; ++r) {
                const int row = crow0 + mi * 16 + r;
                const int col = ccol0 + ni * 16;
                const float v = acc[mi][ni][r];
                if constexpr (MODE == 0) {
                    ((bf16*)Cp)[(long)img * sC + (long)row * ldc + col] = (bf16)(v + bias[col]);
                } else if constexpr (MODE == 1) {
                    ((bf16*)Cp)[(long)img * sC + (long)row * ldc + col] = (bf16)(v + bias[row]);
                } else if constexpr (MODE == 2) {
                    ((float*)Cp)[(long)img * sC + (long)row * ldc + col] =
                        v * scale + rel[(long)img * sRel + (long)row * ldc + col];
                } else {
                    ((float*)Cp)[(long)img * sC + (long)row * ldc + col] = v;
                }
            }
}

// ---------------------------------------------------------------------------
extern "C" void kernel_launch(void* const* d_in, const int* in_sizes, int n_in,
                              void* d_out, int out_size, void* d_ws, size_t ws_size,
                              hipStream_t stream)
{
    const float* box_features = (const float*)d_in[0];
    const float* boxes  = (const float*)d_in[1];
    const float* bn1_g  = (const float*)d_in[2];
    const float* bn1_b  = (const float*)d_in[3];
    const float* Wq     = (const float*)d_in[4];
    const float* bq     = (const float*)d_in[5];
    const float* Wk     = (const float*)d_in[6];
    const float* bk     = (const float*)d_in[7];
    const float* Wv     = (const float*)d_in[8];
    const float* bv     = (const float*)d_in[9];
    const float* Wr     = (const float*)d_in[10];
    const float* br     = (const float*)d_in[11];
    const float* bn2_g  = (const float*)d_in[12];
    const float* bn2_b  = (const float*)d_in[13];
    float* out = (float*)d_out;

    char* ws = (char*)d_ws;
    float* psum   = (float*)(ws + 0);          // 16x1024 f32
    float* psq    = (float*)(ws + 65536);
    float* scale1 = (float*)(ws + 131072);
    float* shift1 = (float*)(ws + 135168);
    float* scale2 = (float*)(ws + 139264);
    float* shift2 = (float*)(ws + 143360);
    float* biasqk = (float*)(ws + 147456);     // 2048 f32
    bf16*  featbf = (bf16*)(ws + 262144);      // 2048x1024 bf16  (4MB)
    bf16*  WqkT   = (bf16*)(ws + 4456448);     // 2048x1024 bf16  (4MB)  [WqT ; WkT]
    bf16*  WvT    = (bf16*)(ws + 8650752);     // 1024x1024 bf16  (2MB)
    bf16*  qkbf   = (bf16*)(ws + 10747904);    // 2048x2048 bf16  (8MB)  [q | k]
    bf16*  vTbf   = (bf16*)(ws + 19136512);    // 4 x 1024x512 bf16 (4MB)
    float* Sbuf   = (float*)(ws + 23330816);   // 4 x 512x512 f32 (4MB), doubles as rel
    bf16*  Pbuf   = (bf16*)(ws + 27525120);    // 4 x 512x512 bf16 (2MB)

    // bn1 over box_features (2048 x 1024)
    colstats_partial<<<dim3(4, 16, 1), dim3(256, 1, 1), 0, stream>>>(box_features, 1024, 128, psum, psq);
    colstats_final<<<dim3(4, 1, 1), dim3(256, 1, 1), 0, stream>>>(psum, psq, 1024, 16, bn1_g, bn1_b, scale1, shift1, 2048.f);
    bn_apply_bf16<<<dim3(2048, 1, 1), dim3(256, 1, 1), 0, stream>>>(box_features, scale1, shift1, featbf, 1023);

    // weights: WqkT = [Wq^T ; Wk^T], WvT = Wv^T (bf16)
    transpose_cvt<<<dim3(16, 16, 3), dim3(64, 4, 1), 0, stream>>>(Wq, Wk, Wv, WqkT, WqkT + 1024 * 1024, WvT);
    pack2<<<dim3(8, 1, 1), dim3(256, 1, 1), 0, stream>>>(bq, bk, biasqk, 1024);

    // [q|k] = feat @ [Wq|Wk] + [bq|bk] : M=2048, N=2048, K=1024 -> bf16
    gemm_bt<0><<<dim3(16, 16, 1), dim3(256, 1, 1), 0, stream>>>(
        featbf, 0, 1024, WqkT, 0, 1024, qkbf, 0, 2048, 1024, biasqk, nullptr, 0, 0.f);

    // vT[img] = Wv^T @ feat[img]^T + bv (per-row) : M=1024, N=512, K=1024 -> bf16
    gemm_bt<1><<<dim3(8, 4, 4), dim3(256, 1, 1), 0, stream>>>(
        WvT, 0, 1024, featbf, 512l * 1024, 1024, vTbf, 1024l * 512, 512, 1024, bv, nullptr, 0, 0.f);

    // rel bias (log_softmax dropped: per-row constant cancels in softmax)
    rel_pe_kernel<<<dim3(512, 4, 1), dim3(256, 1, 1), 0, stream>>>(boxes, Wr, br, Sbuf);

    // S = q @ k^T / 32 + rel : M=512, N=512, K=1024 -> f32 (in place over rel)
    gemm_bt<2><<<dim3(4, 4, 4), dim3(256, 1, 1), 0, stream>>>(
        qkbf, 512l * 2048, 2048, qkbf + 1024, 512l * 2048, 2048,
        Sbuf, 512l * 512, 512, 1024, nullptr, Sbuf, 512l * 512, 0.03125f);

    softmax_rows<<<dim3(2048, 1, 1), dim3(256, 1, 1), 0, stream>>>(Sbuf, Pbuf);

    // out = P @ v = P @ vT^T : M=512, N=1024, K=512 -> f32 into d_out
    gemm_bt<3><<<dim3(4, 8, 4), dim3(256, 1, 1), 0, stream>>>(
        Pbuf, 512l * 512, 512, vTbf, 1024l * 512, 512, out, 512l * 1024, 1024, 512, nullptr, nullptr, 0, 0.f);

    // bn2 over out (2048 x 1024), in place
    colstats_partial<<<dim3(4, 16, 1), dim3(256, 1, 1), 0, stream>>>(out, 1024, 128, psum, psq);
    colstats_final<<<dim3(4, 1, 1), dim3(256, 1, 1), 0, stream>>>(psum, psq, 1024, 16, bn2_g, bn2_b, scale2, shift2, 2048.f);
    bn_apply_f32<<<dim3(2048, 1, 1), dim3(256, 1, 1), 0, stream>>>(out, scale2, shift2, 1023);
}

// Round 2
// 153.037 us; speedup vs baseline: 1.3085x; 1.3085x over previous
//
#include <hip/hip_runtime.h>
#include <math.h>

typedef __bf16 bf16;
typedef __attribute__((ext_vector_type(8))) __bf16 bf16x8;
typedef __attribute__((ext_vector_type(4))) __bf16 bf16x4;
typedef __attribute__((ext_vector_type(4))) float f32x4;

#define NCH 128   // row chunks for column-stats
#define RPC 16    // rows per chunk (NCH*RPC = 2048)

// ---------------- column batchnorm stats (deterministic, two-pass) ----------
// grid = NCH blocks, 256 threads; thread t owns cols 4t..4t+3 (float4).
__global__ __launch_bounds__(256)
void colstats_partial(const float* __restrict__ X, float* __restrict__ psum, float* __restrict__ psq)
{
    const int c4 = threadIdx.x;
    const long r0 = (long)blockIdx.x * RPC;
    const float4* Xv = (const float4*)X;    // row stride = 256 float4
    float4 s = {0.f, 0.f, 0.f, 0.f}, q = {0.f, 0.f, 0.f, 0.f};
#pragma unroll
    for (int r = 0; r < RPC; ++r) {
        float4 x = Xv[(r0 + r) * 256 + c4];
        s.x += x.x; s.y += x.y; s.z += x.z; s.w += x.w;
        q.x += x.x * x.x; q.y += x.y * x.y; q.z += x.z * x.z; q.w += x.w * x.w;
    }
    ((float4*)psum)[blockIdx.x * 256 + c4] = s;
    ((float4*)psq) [blockIdx.x * 256 + c4] = q;
}

__global__ __launch_bounds__(256)
void colstats_final(const float* __restrict__ psum, const float* __restrict__ psq,
                    const float* __restrict__ g, const float* __restrict__ b,
                    float* __restrict__ scale, float* __restrict__ shift, float n)
{
    int col = blockIdx.x * 256 + threadIdx.x;
    float s = 0.f, q = 0.f;
#pragma unroll 8
    for (int ch = 0; ch < NCH; ++ch) { s += psum[ch * 1024 + col]; q += psq[ch * 1024 + col]; }
    float m   = s / n;
    float v   = q / n - m * m;
    float inv = 1.0f / sqrtf(v + 1e-5f);
    float sc  = g[col] * inv;
    scale[col] = sc;
    shift[col] = b[col] - m * sc;
}

// y = bf16(x*scale[col] + shift[col]) , vectorized x4
__global__ void bn_apply_bf16(const float* __restrict__ X, const float* __restrict__ scale,
                              const float* __restrict__ shift, bf16* __restrict__ Y, int Cmask)
{
    long i = (long)blockIdx.x * blockDim.x + threadIdx.x;
    float4 x = ((const float4*)X)[i];
    int col = (int)((i * 4) & Cmask);
    float4 sc = *(const float4*)(scale + col);
    float4 sh = *(const float4*)(shift + col);
    bf16x4 y;
    y[0] = (bf16)(x.x * sc.x + sh.x);
    y[1] = (bf16)(x.y * sc.y + sh.y);
    y[2] = (bf16)(x.z * sc.z + sh.z);
    y[3] = (bf16)(x.w * sc.w + sh.w);
    ((bf16x4*)Y)[i] = y;
}

// in-place f32 x = x*scale[col]+shift[col]
__global__ void bn_apply_f32(float* __restrict__ X, const float* __restrict__ scale,
                             const float* __restrict__ shift, int Cmask)
{
    long i = (long)blockIdx.x * blockDim.x + threadIdx.x;
    float4 x = ((const float4*)X)[i];
    int col = (int)((i * 4) & Cmask);
    float4 sc = *(const float4*)(scale + col);
    float4 sh = *(const float4*)(shift + col);
    float4 r;
    r.x = x.x * sc.x + sh.x;
    r.y = x.y * sc.y + sh.y;
    r.z = x.z * sc.z + sh.z;
    r.w = x.w * sc.w + sh.w;
    ((float4*)X)[i] = r;
}

__global__ void pack2(const float* __restrict__ a, const float* __restrict__ b,
                      float* __restrict__ o, int n)
{
    int i = blockIdx.x * blockDim.x + threadIdx.x;
    o[i] = (i < n) ? a[i] : b[i - n];
}

// 64x64 LDS-tiled transpose + f32->bf16 of the three weight matrices (1024x1024)
__global__ void transpose_cvt(const float* __restrict__ W0, const float* __restrict__ W1,
                              const float* __restrict__ W2,
                              bf16* __restrict__ T0, bf16* __restrict__ T1, bf16* __restrict__ T2)
{
    const float* W; bf16* T;
    if (blockIdx.z == 0)      { W = W0; T = T0; }
    else if (blockIdx.z == 1) { W = W1; T = T1; }
    else                      { W = W2; T = T2; }
    __shared__ float tile[64][65];
    const int bx = blockIdx.x * 64, by = blockIdx.y * 64;
    const int tx = threadIdx.x, ty = threadIdx.y;
#pragma unroll
    for (int i = 0; i < 16; ++i)
        tile[ty + i * 4][tx] = W[(long)(by + ty + i * 4) * 1024 + bx + tx];
    __syncthreads();
#pragma unroll
    for (int i = 0; i < 16; ++i)
        T[(long)(bx + ty + i * 4) * 1024 + by + tx] = (bf16)tile[tx][ty + i * 4];
}

// ------------- relative positional encoding bias rel[img][i][j] -------------
__global__ __launch_bounds__(256)
void rel_pe_kernel(const float* __restrict__ boxes, const float* __restrict__ Wr,
                   const float* __restrict__ brp, float* __restrict__ rel)
{
    const int img = blockIdx.y;
    const int i   = blockIdx.x;
    __shared__ float cx[512], cy[512], wv[512], hv[512];
    __shared__ float wsn[64], wcs[64], tks[16];
    const float* bx = boxes + (long)img * 2048;
    for (int t = threadIdx.x; t < 512; t += 256) {
        float x = bx[t * 4 + 0], y = bx[t * 4 + 1], ww = bx[t * 4 + 2], hh = bx[t * 4 + 3];
        cx[t] = x + 0.5f * ww; cy[t] = y + 0.5f * hh; wv[t] = ww; hv[t] = hh;
    }
    if (threadIdx.x < 64) {
        int c = threadIdx.x >> 4, k = threadIdx.x & 15;
        wsn[threadIdx.x] = Wr[c * 32 + k];        // sin weights
        wcs[threadIdx.x] = Wr[c * 32 + 16 + k];   // cos weights
    }
    if (threadIdx.x < 16)
        tks[threadIdx.x] = exp2f(-1.24572303558f * (float)threadIdx.x); // 1000^(-k/8)
    __syncthreads();
    const float br  = brp[0];
    const float cxi = cx[i], cyi = cy[i], wi = wv[i], hi = hv[i];
    for (int j = threadIdx.x; j < 512; j += 256) {
        const int b  = j >> 7;
        const int jj = 4 * j - b * 512;
        float d[4];
#pragma unroll
        for (int c = 0; c < 4; ++c) {
            const int s = jj + c;
            float dv;
            if (b == 0)      dv = fmaxf(fabsf(cxi - cx[s]) / wv[s], 1e-3f);
            else if (b == 1) dv = fmaxf(fabsf(cyi - cy[s]) / hv[s], 1e-3f);
            else if (b == 2) dv = wi / wv[s];
            else             dv = hi / hv[s];
            d[c] = logf(dv);
        }
        float acc = br;
#pragma unroll
        for (int c = 0; c < 4; ++c)
#pragma unroll
            for (int k = 0; k < 16; ++k) {
                float s_, c_;
                __sincosf(d[c] * tks[k], &s_, &c_);
                acc += s_ * wsn[c * 16 + k] + c_ * wcs[c * 16 + k];
            }
        rel[((long)img * 512 + i) * 512 + j] = acc;
    }
}

// ---------------- row softmax (512 wide) f32 -> bf16 ------------------------
__global__ __launch_bounds__(256)
void softmax_rows(const float* __restrict__ S, bf16* __restrict__ P)
{
    const long row = blockIdx.x;
    const float* s = S + row * 512;
    const int t = threadIdx.x;
    float x0 = s[t], x1 = s[t + 256];
    float mx = fmaxf(x0, x1);
#pragma unroll
    for (int off = 32; off; off >>= 1) mx = fmaxf(mx, __shfl_xor(mx, off));
    __shared__ float redm[4], reds[4];
    if ((t & 63) == 0) redm[t >> 6] = mx;
    __syncthreads();
    mx = fmaxf(fmaxf(redm[0], redm[1]), fmaxf(redm[2], redm[3]));
    float e0 = __expf(x0 - mx), e1 = __expf(x1 - mx);
    float sm = e0 + e1;
#pragma unroll
    for (int off = 32; off; off >>= 1) sm += __shfl_xor(sm, off);
    if ((t & 63) == 0) reds[t >> 6] = sm;
    __syncthreads();
    sm = (reds[0] + reds[1]) + (reds[2] + reds[3]);
    float inv = 1.0f / sm;
    P[row * 512 + t]       = (bf16)(e0 * inv);
    P[row * 512 + t + 256] = (bf16)(e1 * inv);
}

// ---------------- MFMA GEMM: C = A(M,K) @ BT(N,K)^T -------------------------
__device__ __forceinline__ void stage_tile_128x32(const bf16* __restrict__ src_base, int ld,
                                                  int row0, int k0, bf16* lds_base, int w, int l)
{
#pragma unroll
    for (int t = 0; t < 2; ++t) {
        int rchunk = w * 32 + t * 16;
        const bf16* src = src_base + (long)(row0 + rchunk + (l >> 2)) * ld + k0 + (l & 3) * 8;
        __builtin_amdgcn_global_load_lds((__attribute__((address_space(1))) void*)src,
                                         (__attribute__((address_space(3))) void*)(lds_base + rchunk * 32),
                                         16, 0, 0);
    }
}

// MODE 0: bf16 out, +bias[col]   1: bf16 out, +bias[row]
// MODE 2: f32 out = acc*scale + rel[row,col]   3: f32 out
template <int MODE>
__global__ __launch_bounds__(256, 2)
void gemm_bt(const bf16* __restrict__ A, long sA, int lda,
             const bf16* __restrict__ B, long sB, int ldb,
             void* __restrict__ Cp, long sC, int ldc,
             int K,
             const float* __restrict__ bias,
             const float* __restrict__ rel, long sRel, float scale)
{
    __shared__ bf16 As[2][128 * 32];
    __shared__ bf16 Bs[2][128 * 32];
    const int img = blockIdx.z;
    const bf16* Ab = A + (long)img * sA;
    const bf16* Bb = B + (long)img * sB;
    const int bm = blockIdx.x * 128;
    const int bn = blockIdx.y * 128;
    const int tid = threadIdx.x;
    const int w = tid >> 6, l = tid & 63;
    const int wr = w >> 1, wc = w & 1;

    f32x4 acc[4][4];
#pragma unroll
    for (int i = 0; i < 4; ++i)
#pragma unroll
        for (int j = 0; j < 4; ++j) acc[i][j] = (f32x4){0.f, 0.f, 0.f, 0.f};

    const int nkt = K >> 5;
    stage_tile_128x32(Ab, lda, bm, 0, &As[0][0], w, l);
    stage_tile_128x32(Bb, ldb, bn, 0, &Bs[0][0], w, l);
    __syncthreads();

    const int fr = l & 15;
    const int ko = (l >> 4) * 8;

    for (int kt = 0; kt < nkt; ++kt) {
        const int cur = kt & 1;
        if (kt + 1 < nkt) {
            stage_tile_128x32(Ab, lda, bm, (kt + 1) << 5, &As[cur ^ 1][0], w, l);
            stage_tile_128x32(Bb, ldb, bn, (kt + 1) << 5, &Bs[cur ^ 1][0], w, l);
        }
        bf16x8 af[4], bfv[4];
#pragma unroll
        for (int mi = 0; mi < 4; ++mi)
            af[mi] = *(const bf16x8*)(&As[cur][(wr * 64 + mi * 16 + fr) * 32 + ko]);
#pragma unroll
        for (int ni = 0; ni < 4; ++ni)
            bfv[ni] = *(const bf16x8*)(&Bs[cur][(wc * 64 + ni * 16 + fr) * 32 + ko]);
#pragma unroll
        for (int mi = 0; mi < 4; ++mi)
#pragma unroll
            for (int ni = 0; ni < 4; ++ni)
                acc[mi][ni] = __builtin_amdgcn_mfma_f32_16x16x32_bf16(af[mi], bfv[ni], acc[mi][ni], 0, 0, 0);
        __syncthreads();
    }

    const int crow0 = bm + wr * 64 + (l >> 4) * 4;
    const int ccol0 = bn + wc * 64 + fr;
#pragma unroll
    for (int mi = 0; mi < 4; ++mi)
#pragma unroll
        for (int ni = 0; ni < 4; ++ni)
#pragma unroll
            for (int r = 0; r < 4; ++r) {
                const int row = crow0 + mi * 16 + r;
                const int col = ccol0 + ni * 16;
                const float v = acc[mi][ni][r];
                if constexpr (MODE == 0) {
                    ((bf16*)Cp)[(long)img * sC + (long)row * ldc + col] = (bf16)(v + bias[col]);
                } else if constexpr (MODE == 1) {
                    ((bf16*)Cp)[(long)img * sC + (long)row * ldc + col] = (bf16)(v + bias[row]);
                } else if constexpr (MODE == 2) {
                    ((float*)Cp)[(long)img * sC + (long)row * ldc + col] =
                        v * scale + rel[(long)img * sRel + (long)row * ldc + col];
                } else {
                    ((float*)Cp)[(long)img * sC + (long)row * ldc + col] = v;
                }
            }
}

// ---------------------------------------------------------------------------
extern "C" void kernel_launch(void* const* d_in, const int* in_sizes, int n_in,
                              void* d_out, int out_size, void* d_ws, size_t ws_size,
                              hipStream_t stream)
{
    const float* box_features = (const float*)d_in[0];
    const float* boxes  = (const float*)d_in[1];
    const float* bn1_g  = (const float*)d_in[2];
    const float* bn1_b  = (const float*)d_in[3];
    const float* Wq     = (const float*)d_in[4];
    const float* bq     = (const float*)d_in[5];
    const float* Wk     = (const float*)d_in[6];
    const float* bk     = (const float*)d_in[7];
    const float* Wv     = (const float*)d_in[8];
    const float* bv     = (const float*)d_in[9];
    const float* Wr     = (const float*)d_in[10];
    const float* br     = (const float*)d_in[11];
    const float* bn2_g  = (const float*)d_in[12];
    const float* bn2_b  = (const float*)d_in[13];
    float* out = (float*)d_out;

    char* ws = (char*)d_ws;
    const long MB = 1024 * 1024;
    float* psum   = (float*)(ws + 0);            // NCH x 1024 f32 (512KB)
    float* psq    = (float*)(ws + 512 * 1024);   // 512KB
    float* scale1 = (float*)(ws + 1 * MB);
    float* shift1 = (float*)(ws + 1 * MB + 4096);
    float* scale2 = (float*)(ws + 1 * MB + 8192);
    float* shift2 = (float*)(ws + 1 * MB + 12288);
    float* biasqk = (float*)(ws + 1 * MB + 16384);  // 2048 f32
    bf16*  featbf = (bf16*)(ws + 2 * MB);        // 2048x1024 bf16  (4MB)
    bf16*  WqkT   = (bf16*)(ws + 6 * MB);        // 2048x1024 bf16  (4MB)
    bf16*  WvT    = (bf16*)(ws + 10 * MB);       // 1024x1024 bf16  (2MB)
    bf16*  qkbf   = (bf16*)(ws + 12 * MB);       // 2048x2048 bf16  (8MB)
    bf16*  vTbf   = (bf16*)(ws + 20 * MB);       // 4 x 1024x512 bf16 (4MB)
    float* Sbuf   = (float*)(ws + 24 * MB);      // 4 x 512x512 f32 (4MB)
    bf16*  Pbuf   = (bf16*)(ws + 28 * MB);       // 4 x 512x512 bf16 (2MB)

    // bn1 over box_features (2048 x 1024)
    colstats_partial<<<dim3(NCH, 1, 1), dim3(256, 1, 1), 0, stream>>>(box_features, psum, psq);
    colstats_final<<<dim3(4, 1, 1), dim3(256, 1, 1), 0, stream>>>(psum, psq, bn1_g, bn1_b, scale1, shift1, 2048.f);
    bn_apply_bf16<<<dim3(2048, 1, 1), dim3(256, 1, 1), 0, stream>>>(box_features, scale1, shift1, featbf, 1023);

    // weights: WqkT = [Wq^T ; Wk^T], WvT = Wv^T (bf16)
    transpose_cvt<<<dim3(16, 16, 3), dim3(64, 4, 1), 0, stream>>>(Wq, Wk, Wv, WqkT, WqkT + 1024 * 1024, WvT);
    pack2<<<dim3(8, 1, 1), dim3(256, 1, 1), 0, stream>>>(bq, bk, biasqk, 1024);

    // [q|k] = feat @ [Wq|Wk] + [bq|bk] : M=2048, N=2048, K=1024 -> bf16
    gemm_bt<0><<<dim3(16, 16, 1), dim3(256, 1, 1), 0, stream>>>(
        featbf, 0, 1024, WqkT, 0, 1024, qkbf, 0, 2048, 1024, biasqk, nullptr, 0, 0.f);

    // vT[img] = Wv^T @ feat[img]^T + bv (per-row) : M=1024, N=512, K=1024 -> bf16
    gemm_bt<1><<<dim3(8, 4, 4), dim3(256, 1, 1), 0, stream>>>(
        WvT, 0, 1024, featbf, 512l * 1024, 1024, vTbf, 1024l * 512, 512, 1024, bv, nullptr, 0, 0.f);

    // rel bias (log_softmax dropped: per-row constant cancels in softmax)
    rel_pe_kernel<<<dim3(512, 4, 1), dim3(256, 1, 1), 0, stream>>>(boxes, Wr, br, Sbuf);

    // S = q @ k^T / 32 + rel : M=512, N=512, K=1024 -> f32 (in place over rel)
    gemm_bt<2><<<dim3(4, 4, 4), dim3(256, 1, 1), 0, stream>>>(
        qkbf, 512l * 2048, 2048, qkbf + 1024, 512l * 2048, 2048,
        Sbuf, 512l * 512, 512, 1024, nullptr, Sbuf, 512l * 512, 0.03125f);

    softmax_rows<<<dim3(2048, 1, 1), dim3(256, 1, 1), 0, stream>>>(Sbuf, Pbuf);

    // out = P @ v = P @ vT^T : M=512, N=1024, K=512 -> f32 into d_out
    gemm_bt<3><<<dim3(4, 8, 4), dim3(256, 1, 1), 0, stream>>>(
        Pbuf, 512l * 512, 512, vTbf, 1024l * 512, 512, out, 512l * 1024, 1024, 512, nullptr, nullptr, 0, 0.f);

    // bn2 over out (2048 x 1024), in place
    colstats_partial<<<dim3(NCH, 1, 1), dim3(256, 1, 1), 0, stream>>>(out, psum, psq);
    colstats_final<<<dim3(4, 1, 1), dim3(256, 1, 1), 0, stream>>>(psum, psq, bn2_g, bn2_b, scale2, shift2, 2048.f);
    bn_apply_f32<<<dim3(2048, 1, 1), dim3(256, 1, 1), 0, stream>>>(out, scale2, shift2, 1023);
}

// Round 3
// 112.130 us; speedup vs baseline: 1.7859x; 1.3648x over previous
//
#include <hip/hip_runtime.h>
#include <math.h>

typedef __bf16 bf16;
typedef __attribute__((ext_vector_type(8))) __bf16 bf16x8;
typedef __attribute__((ext_vector_type(4))) __bf16 bf16x4;
typedef __attribute__((ext_vector_type(4))) float f32x4;

#define NCH1 128  // row chunks for bn1 stats
#define RPC1 16   // rows per chunk

// ---------------- bn1 column stats: partial sums ----------------------------
__global__ __launch_bounds__(256)
void colstats_partial(const float* __restrict__ X, float* __restrict__ psum, float* __restrict__ psq)
{
    const int c4 = threadIdx.x;
    const long r0 = (long)blockIdx.x * RPC1;
    const float4* Xv = (const float4*)X;
    float4 s = {0.f,0.f,0.f,0.f}, q = {0.f,0.f,0.f,0.f};
#pragma unroll
    for (int r = 0; r < RPC1; ++r) {
        float4 x = Xv[(r0 + r) * 256 + c4];
        s.x += x.x; s.y += x.y; s.z += x.z; s.w += x.w;
        q.x += x.x*x.x; q.y += x.y*x.y; q.z += x.z*x.z; q.w += x.w*x.w;
    }
    ((float4*)psum)[blockIdx.x * 256 + c4] = s;
    ((float4*)psq) [blockIdx.x * 256 + c4] = q;
}

// ------- fused: finalize stats (per 64-col stripe) + apply BN ---------------
// grid (16 col-stripes, 16 row-chunks), 256 threads.
template <int NCH_, int BF16OUT>
__global__ __launch_bounds__(256)
void bn_final_apply(const float* __restrict__ X, const float* __restrict__ psum,
                    const float* __restrict__ psq, const float* __restrict__ g,
                    const float* __restrict__ b, void* __restrict__ Yp)
{
    __shared__ float ls[4][64], lq[4][64], ssc[64], ssh[64];
    const int t  = threadIdx.x;
    const int cs = blockIdx.x;
    const int rc = blockIdx.y;
    const int col_l = t & 63, part = t >> 6;
    const int col = cs * 64 + col_l;
    constexpr int CPT = NCH_ / 4;
    float s = 0.f, q = 0.f;
#pragma unroll
    for (int i = 0; i < CPT; ++i) {
        int ch = part * CPT + i;
        s += psum[ch * 1024 + col];
        q += psq [ch * 1024 + col];
    }
    ls[part][col_l] = s; lq[part][col_l] = q;
    __syncthreads();
    if (t < 64) {
        float S = ls[0][t]+ls[1][t]+ls[2][t]+ls[3][t];
        float Q = lq[0][t]+lq[1][t]+lq[2][t]+lq[3][t];
        float m = S / 2048.f;
        float v = Q / 2048.f - m*m;
        float inv = 1.0f / sqrtf(v + 1e-5f);
        float sc = g[cs*64+t] * inv;
        ssc[t] = sc; ssh[t] = b[cs*64+t] - m*sc;
    }
    __syncthreads();
    const int f = t & 15, rsub = t >> 4;
    float4 sc4 = ((const float4*)ssc)[f];
    float4 sh4 = ((const float4*)ssh)[f];
#pragma unroll
    for (int it = 0; it < 8; ++it) {
        int row = rc*128 + it*16 + rsub;
        float4 x = ((const float4*)(X + (long)row*1024 + cs*64))[f];
        float4 rv;
        rv.x = x.x*sc4.x + sh4.x;
        rv.y = x.y*sc4.y + sh4.y;
        rv.z = x.z*sc4.z + sh4.z;
        rv.w = x.w*sc4.w + sh4.w;
        if constexpr (BF16OUT) {
            bf16x4 y;
            y[0]=(bf16)rv.x; y[1]=(bf16)rv.y; y[2]=(bf16)rv.z; y[3]=(bf16)rv.w;
            ((bf16x4*)((bf16*)Yp + (long)row*1024 + cs*64))[f] = y;
        } else {
            ((float4*)((float*)Yp + (long)row*1024 + cs*64))[f] = rv;
        }
    }
}

// ---- weight transpose f32->bf16 (3x 1024x1024) + bias pack fused ----------
__global__ void transpose_cvt(const float* __restrict__ W0, const float* __restrict__ W1,
                              const float* __restrict__ W2,
                              bf16* __restrict__ T0, bf16* __restrict__ T1, bf16* __restrict__ T2,
                              const float* __restrict__ bq, const float* __restrict__ bk,
                              float* __restrict__ biasqk)
{
    const float* W; bf16* T;
    if (blockIdx.z == 0)      { W = W0; T = T0; }
    else if (blockIdx.z == 1) { W = W1; T = T1; }
    else                      { W = W2; T = T2; }
    __shared__ float tile[64][65];
    const int bx = blockIdx.x * 64, by = blockIdx.y * 64;
    const int tx = threadIdx.x, ty = threadIdx.y;
#pragma unroll
    for (int i = 0; i < 16; ++i)
        tile[ty + i * 4][tx] = W[(long)(by + ty + i * 4) * 1024 + bx + tx];
    __syncthreads();
#pragma unroll
    for (int i = 0; i < 16; ++i)
        T[(long)(bx + ty + i * 4) * 1024 + by + tx] = (bf16)tile[tx][ty + i * 4];
    if (blockIdx.z == 2 && blockIdx.x == 0 && blockIdx.y == 0) {
        int t = ty * 64 + tx;
        for (int i = t; i < 2048; i += 256)
            biasqk[i] = (i < 1024) ? bq[i] : bk[i - 1024];
    }
}

// ---------------- MFMA GEMM body: C = A(M,K) @ BT(N,K)^T --------------------
__device__ __forceinline__ void stage_tile_128x32(const bf16* __restrict__ src_base, int ld,
                                                  int row0, int k0, bf16* lds_base, int w, int l)
{
#pragma unroll
    for (int t = 0; t < 2; ++t) {
        int rchunk = w * 32 + t * 16;
        const bf16* src = src_base + (long)(row0 + rchunk + (l >> 2)) * ld + k0 + (l & 3) * 8;
        __builtin_amdgcn_global_load_lds((__attribute__((address_space(1))) void*)src,
                                         (__attribute__((address_space(3))) void*)(lds_base + rchunk * 32),
                                         16, 0, 0);
    }
}

// MODE 0: bf16 out +bias[col]   1: bf16 out +bias[row]
// MODE 2: f32 out = acc*scale + rel[row,col] (in-place safe)
// MODE 4: f32 out = acc*scale
// MODE 6: f32 out = acc ; also emit per-tile column stats into psum/psq[chunk]
template <int MODE>
__device__ __forceinline__ void gemm_body(
    const bf16* __restrict__ Ab, int lda, const bf16* __restrict__ Bb, int ldb,
    void* __restrict__ Cp, int ldc, int K, int bm, int bn,
    const float* __restrict__ bias, const float* __restrict__ rel, int ldrel, float scale,
    float* __restrict__ psum, float* __restrict__ psq, int chunk, char* smem)
{
    bf16* As0 = (bf16*)smem;             // [2][128*32]
    bf16* Bs0 = (bf16*)(smem + 16384);
    const int tid = threadIdx.x;
    const int w = tid >> 6, l = tid & 63;
    const int wr = w >> 1, wc = w & 1;

    f32x4 acc[4][4];
#pragma unroll
    for (int i = 0; i < 4; ++i)
#pragma unroll
        for (int j = 0; j < 4; ++j) acc[i][j] = (f32x4){0.f,0.f,0.f,0.f};

    const int nkt = K >> 5;
    stage_tile_128x32(Ab, lda, bm, 0, As0, w, l);
    stage_tile_128x32(Bb, ldb, bn, 0, Bs0, w, l);
    __syncthreads();

    const int fr = l & 15;
    const int ko = (l >> 4) * 8;

    for (int kt = 0; kt < nkt; ++kt) {
        const int cur = kt & 1;
        bf16* Asc = As0 + cur * 4096;
        bf16* Bsc = Bs0 + cur * 4096;
        if (kt + 1 < nkt) {
            stage_tile_128x32(Ab, lda, bm, (kt + 1) << 5, As0 + (cur ^ 1) * 4096, w, l);
            stage_tile_128x32(Bb, ldb, bn, (kt + 1) << 5, Bs0 + (cur ^ 1) * 4096, w, l);
        }
        bf16x8 af[4], bfv[4];
#pragma unroll
        for (int mi = 0; mi < 4; ++mi)
            af[mi] = *(const bf16x8*)(&Asc[(wr * 64 + mi * 16 + fr) * 32 + ko]);
#pragma unroll
        for (int ni = 0; ni < 4; ++ni)
            bfv[ni] = *(const bf16x8*)(&Bsc[(wc * 64 + ni * 16 + fr) * 32 + ko]);
#pragma unroll
        for (int mi = 0; mi < 4; ++mi)
#pragma unroll
            for (int ni = 0; ni < 4; ++ni)
                acc[mi][ni] = __builtin_amdgcn_mfma_f32_16x16x32_bf16(af[mi], bfv[ni], acc[mi][ni], 0, 0, 0);
        __syncthreads();
    }

    // C/D layout: col = lane&15, row = (lane>>4)*4 + reg
    const int crow0 = bm + wr * 64 + (l >> 4) * 4;
    const int ccol0 = bn + wc * 64 + fr;
#pragma unroll
    for (int mi = 0; mi < 4; ++mi)
#pragma unroll
        for (int ni = 0; ni < 4; ++ni)
#pragma unroll
            for (int r = 0; r < 4; ++r) {
                const int row = crow0 + mi * 16 + r;
                const int col = ccol0 + ni * 16;
                const float v = acc[mi][ni][r];
                if constexpr (MODE == 0) {
                    ((bf16*)Cp)[(long)row * ldc + col] = (bf16)(v + bias[col]);
                } else if constexpr (MODE == 1) {
                    ((bf16*)Cp)[(long)row * ldc + col] = (bf16)(v + bias[row]);
                } else if constexpr (MODE == 2) {
                    ((float*)Cp)[(long)row * ldc + col] = v * scale + rel[(long)row * ldrel + col];
                } else if constexpr (MODE == 4) {
                    ((float*)Cp)[(long)row * ldc + col] = v * scale;
                } else {
                    ((float*)Cp)[(long)row * ldc + col] = v;
                }
            }

    if constexpr (MODE == 6) {
        // deterministic per-tile column stats from registers
        float cs_[4], cq_[4];
#pragma unroll
        for (int ni = 0; ni < 4; ++ni) {
            float s = 0.f, q = 0.f;
#pragma unroll
            for (int mi = 0; mi < 4; ++mi)
#pragma unroll
                for (int r = 0; r < 4; ++r) { float v = acc[mi][ni][r]; s += v; q += v * v; }
            cs_[ni] = s; cq_[ni] = q;
        }
#pragma unroll
        for (int ni = 0; ni < 4; ++ni) {
            cs_[ni] += __shfl_xor(cs_[ni], 16); cs_[ni] += __shfl_xor(cs_[ni], 32);
            cq_[ni] += __shfl_xor(cq_[ni], 16); cq_[ni] += __shfl_xor(cq_[ni], 32);
        }
        float* lred = (float*)smem;   // 512 floats, reuse staging LDS
        __syncthreads();
        if (l < 16) {
#pragma unroll
            for (int ni = 0; ni < 4; ++ni) {
                int c = wc * 64 + ni * 16 + l;
                lred[(wr * 2 + 0) * 128 + c] = cs_[ni];
                lred[(wr * 2 + 1) * 128 + c] = cq_[ni];
            }
        }
        __syncthreads();
        if (tid < 128) {
            float st = lred[0 * 128 + tid] + lred[2 * 128 + tid];
            float qt = lred[1 * 128 + tid] + lred[3 * 128 + tid];
            psum[chunk * 1024 + bn + tid] = st;
            psq [chunk * 1024 + bn + tid] = qt;
        }
    }
}

// ------------- relative positional encoding (2 rows per block) --------------
__device__ __forceinline__ void rel_body(const float* __restrict__ boxes, const float* __restrict__ Wr,
                                         const float* __restrict__ brp, float* __restrict__ rel,
                                         int img, int pair, char* smem)
{
    float* cx  = (float*)smem;
    float* cy  = cx + 512;
    float* wv  = cy + 512;
    float* hv  = wv + 512;
    float* wsn = hv + 512;
    float* wcs = wsn + 64;
    float* tks = wcs + 64;
    const float* bx = boxes + (long)img * 2048;
    for (int t = threadIdx.x; t < 512; t += 256) {
        float x = bx[t*4+0], y = bx[t*4+1], ww = bx[t*4+2], hh = bx[t*4+3];
        cx[t] = x + 0.5f*ww; cy[t] = y + 0.5f*hh; wv[t] = ww; hv[t] = hh;
    }
    if (threadIdx.x < 64) {
        int c = threadIdx.x >> 4, k = threadIdx.x & 15;
        wsn[threadIdx.x] = Wr[c * 32 + k];
        wcs[threadIdx.x] = Wr[c * 32 + 16 + k];
    }
    if (threadIdx.x < 16)
        tks[threadIdx.x] = exp2f(-1.24572303558f * (float)threadIdx.x);
    __syncthreads();
    const float br = brp[0];
#pragma unroll
    for (int ii = 0; ii < 2; ++ii) {
        const int i = pair * 2 + ii;
        const float cxi = cx[i], cyi = cy[i], wi = wv[i], hi = hv[i];
        for (int j = threadIdx.x; j < 512; j += 256) {
            const int b  = j >> 7;
            const int jj = 4 * j - b * 512;
            float d[4];
#pragma unroll
            for (int c = 0; c < 4; ++c) {
                const int s = jj + c;
                float dv;
                if (b == 0)      dv = fmaxf(fabsf(cxi - cx[s]) / wv[s], 1e-3f);
                else if (b == 1) dv = fmaxf(fabsf(cyi - cy[s]) / hv[s], 1e-3f);
                else if (b == 2) dv = wi / wv[s];
                else             dv = hi / hv[s];
                d[c] = logf(dv);
            }
            float acc = br;
#pragma unroll
            for (int c = 0; c < 4; ++c)
#pragma unroll
                for (int k = 0; k < 16; ++k) {
                    float s_, c_;
                    __sincosf(d[c] * tks[k], &s_, &c_);
                    acc += s_ * wsn[c * 16 + k] + c_ * wcs[c * 16 + k];
                }
            rel[((long)img * 512 + i) * 512 + j] = acc;
        }
    }
}

// --------- heterogeneous mega-kernel: qk GEMM + vT GEMM + rel-PE ------------
// 1408 blocks = 128 groups x 11 {2 qk, 1 vT, 8 rel} (interleave mixes MFMA- and
// trans-bound blocks on each CU so the pipes overlap).
__global__ __launch_bounds__(256, 2)
void megaD(const bf16* __restrict__ featbf, const bf16* __restrict__ WqkT,
           const bf16* __restrict__ WvT, bf16* __restrict__ qkbf, bf16* __restrict__ vTbf,
           const float* __restrict__ biasqk, const float* __restrict__ bv,
           const float* __restrict__ boxes, const float* __restrict__ Wr,
           const float* __restrict__ br, float* __restrict__ relbuf)
{
    __shared__ char smem[32768];
    const unsigned bid = blockIdx.x;
    const unsigned g = bid / 11u, r = bid % 11u;
    if (r < 2) {
        const unsigned t = g * 2 + r;           // 0..255
        const int bmi = t & 15, bni = t >> 4;
        gemm_body<0>(featbf, 1024, WqkT, 1024, qkbf, 2048, 1024, bmi * 128, bni * 128,
                     biasqk, nullptr, 0, 0.f, nullptr, nullptr, 0, smem);
    } else if (r == 2) {
        const int img = g >> 5, rem = g & 31, mi = rem >> 2, ni = rem & 3;
        gemm_body<1>(WvT, 1024, featbf + (long)img * 512 * 1024, 1024,
                     vTbf + (long)img * 1024 * 512, 512, 1024, mi * 128, ni * 128,
                     bv, nullptr, 0, 0.f, nullptr, nullptr, 0, smem);
    } else {
        const unsigned idx = g * 8 + (r - 3);   // 0..1023
        rel_body(boxes, Wr, br, relbuf, idx >> 8, idx & 255, smem);
    }
}

// --------- S = q@k^T/32 + rel, split-K (two halves of K=1024) --------------
__global__ __launch_bounds__(256, 2)
void attn_s(const bf16* __restrict__ qk, float* __restrict__ S0, float* __restrict__ S1)
{
    __shared__ char smem[32768];
    const int z = blockIdx.z, img = z >> 1, kh = z & 1;
    const bf16* A = qk + (long)img * 512 * 2048 + kh * 512;
    const bf16* B = qk + 1024 + (long)img * 512 * 2048 + kh * 512;
    const int bm = blockIdx.x * 128, bn = blockIdx.y * 128;
    if (kh == 0)
        gemm_body<2>(A, 2048, B, 2048, S0 + (long)img * 512 * 512, 512, 512, bm, bn,
                     nullptr, S0 + (long)img * 512 * 512, 512, 0.03125f, nullptr, nullptr, 0, smem);
    else
        gemm_body<4>(A, 2048, B, 2048, S1 + (long)img * 512 * 512, 512, 512, bm, bn,
                     nullptr, nullptr, 0, 0.03125f, nullptr, nullptr, 0, smem);
}

// ---------------- row softmax over S0+S1 (512 wide) -> bf16 -----------------
__global__ __launch_bounds__(256)
void softmax2(const float* __restrict__ S0, const float* __restrict__ S1, bf16* __restrict__ P)
{
    const long row = blockIdx.x;
    const int t = threadIdx.x;
    float x0 = S0[row * 512 + t]       + S1[row * 512 + t];
    float x1 = S0[row * 512 + t + 256] + S1[row * 512 + t + 256];
    float mx = fmaxf(x0, x1);
#pragma unroll
    for (int off = 32; off; off >>= 1) mx = fmaxf(mx, __shfl_xor(mx, off));
    __shared__ float redm[4], reds[4];
    if ((t & 63) == 0) redm[t >> 6] = mx;
    __syncthreads();
    mx = fmaxf(fmaxf(redm[0], redm[1]), fmaxf(redm[2], redm[3]));
    float e0 = __expf(x0 - mx), e1 = __expf(x1 - mx);
    float sm = e0 + e1;
#pragma unroll
    for (int off = 32; off; off >>= 1) sm += __shfl_xor(sm, off);
    if ((t & 63) == 0) reds[t >> 6] = sm;
    __syncthreads();
    sm = (reds[0] + reds[1]) + (reds[2] + reds[3]);
    float inv = 1.0f / sm;
    P[row * 512 + t]       = (bf16)(e0 * inv);
    P[row * 512 + t + 256] = (bf16)(e1 * inv);
}

// ---------------- out = P @ vT^T, + bn2 column partials ---------------------
__global__ __launch_bounds__(256, 2)
void pv_gemm(const bf16* __restrict__ P, const bf16* __restrict__ vT, float* __restrict__ out,
             float* __restrict__ psum, float* __restrict__ psq)
{
    __shared__ char smem[32768];
    const int img = blockIdx.z;
    const int bm = blockIdx.x * 128, bn = blockIdx.y * 128;
    gemm_body<6>(P + (long)img * 512 * 512, 512, vT + (long)img * 1024 * 512, 512,
                 out + (long)img * 512 * 1024, 1024, 512, bm, bn,
                 nullptr, nullptr, 0, 0.f, psum, psq, img * 4 + blockIdx.x, smem);
}

// ---------------------------------------------------------------------------
extern "C" void kernel_launch(void* const* d_in, const int* in_sizes, int n_in,
                              void* d_out, int out_size, void* d_ws, size_t ws_size,
                              hipStream_t stream)
{
    const float* box_features = (const float*)d_in[0];
    const float* boxes  = (const float*)d_in[1];
    const float* bn1_g  = (const float*)d_in[2];
    const float* bn1_b  = (const float*)d_in[3];
    const float* Wq     = (const float*)d_in[4];
    const float* bq     = (const float*)d_in[5];
    const float* Wk     = (const float*)d_in[6];
    const float* bk     = (const float*)d_in[7];
    const float* Wv     = (const float*)d_in[8];
    const float* bv     = (const float*)d_in[9];
    const float* Wr     = (const float*)d_in[10];
    const float* br     = (const float*)d_in[11];
    const float* bn2_g  = (const float*)d_in[12];
    const float* bn2_b  = (const float*)d_in[13];
    float* out = (float*)d_out;

    char* ws = (char*)d_ws;
    const long MB = 1024 * 1024;
    float* psum   = (float*)(ws + 0);            // up to 128x1024 f32
    float* psq    = (float*)(ws + 512 * 1024);
    float* biasqk = (float*)(ws + 1 * MB);       // 2048 f32
    bf16*  featbf = (bf16*)(ws + 2 * MB);        // 2048x1024 bf16 (4MB)
    bf16*  WqkT   = (bf16*)(ws + 6 * MB);        // 2048x1024 bf16 (4MB) [WqT;WkT]
    float* Sbuf1  = (float*)(ws + 6 * MB);       // aliases WqkT (dead after megaD)
    bf16*  WvT    = (bf16*)(ws + 10 * MB);       // 1024x1024 bf16 (2MB)
    bf16*  qkbf   = (bf16*)(ws + 12 * MB);       // 2048x2048 bf16 (8MB)
    bf16*  vTbf   = (bf16*)(ws + 20 * MB);       // 4x1024x512 bf16 (4MB)
    float* Sbuf0  = (float*)(ws + 24 * MB);      // 4x512x512 f32 (4MB), rel then S
    bf16*  Pbuf   = (bf16*)(ws + 28 * MB);       // 4x512x512 bf16 (2MB)

    transpose_cvt<<<dim3(16, 16, 3), dim3(64, 4, 1), 0, stream>>>(
        Wq, Wk, Wv, WqkT, WqkT + 1024 * 1024, WvT, bq, bk, biasqk);

    colstats_partial<<<dim3(NCH1, 1, 1), dim3(256, 1, 1), 0, stream>>>(box_features, psum, psq);

    bn_final_apply<NCH1, 1><<<dim3(16, 16, 1), dim3(256, 1, 1), 0, stream>>>(
        box_features, psum, psq, bn1_g, bn1_b, featbf);

    megaD<<<dim3(1408, 1, 1), dim3(256, 1, 1), 0, stream>>>(
        featbf, WqkT, WvT, qkbf, vTbf, biasqk, bv, boxes, Wr, br, Sbuf0);

    attn_s<<<dim3(4, 4, 8), dim3(256, 1, 1), 0, stream>>>(qkbf, Sbuf0, Sbuf1);

    softmax2<<<dim3(2048, 1, 1), dim3(256, 1, 1), 0, stream>>>(Sbuf0, Sbuf1, Pbuf);

    pv_gemm<<<dim3(4, 8, 4), dim3(256, 1, 1), 0, stream>>>(Pbuf, vTbf, out, psum, psq);

    bn_final_apply<16, 0><<<dim3(16, 16, 1), dim3(256, 1, 1), 0, stream>>>(
        out, psum, psq, bn2_g, bn2_b, out);
}